// Round 1
// baseline (130.752 us; speedup 1.0000x reference)
//
#include <hip/hip_runtime.h>

// Problem constants (match reference)
#define BATCH 16
#define IMG_H 1024
#define IMG_W 1024
#define HALO 4              // 9x9 window
#define TX 128              // output tile cols
#define TY 16               // output tile rows
#define IN_W (TX + 2*HALO)  // 136
#define IN_H (TY + 2*HALO)  // 24
#define NTHREADS 256

__global__ void wbce_zero_kernel(float* out) { out[0] = 0.0f; }

__global__ __launch_bounds__(NTHREADS, 4)
void wbce_kernel(const float* __restrict__ logits,
                 const float* __restrict__ targets,
                 float* __restrict__ out)
{
    __shared__ float sT[IN_H][IN_W];     // targets tile with halo; OOB = -1.0f
    __shared__ float sHmax[IN_H][TX];    // horizontal 9-max
    __shared__ float sHmin[IN_H][TX];    // horizontal 9-min
    __shared__ float sRed[NTHREADS / 64];

    const int tid = threadIdx.x;
    const int colBase = blockIdx.x * TX;
    const int rowBase = blockIdx.y * TY;
    const int b = blockIdx.z;

    const float* tgt = targets + (size_t)b * (IMG_H * IMG_W);
    const float* lg  = logits  + (size_t)b * (IMG_H * IMG_W);

    // ---- stage targets tile (with halo) into LDS; OOB sentinel = -1 ----
    for (int i = tid; i < IN_H * IN_W; i += NTHREADS) {
        int r = i / IN_W;
        int c = i - r * IN_W;
        int gr = rowBase + r - HALO;
        int gc = colBase + c - HALO;
        float v = -1.0f;
        if (gr >= 0 && gr < IMG_H && gc >= 0 && gc < IMG_W)
            v = tgt[gr * IMG_W + gc];
        sT[r][c] = v;
    }
    __syncthreads();

    // ---- horizontal pass: 9-wide min/max per (row, out-col) ----
    // OOB (-1) is neutral for max (valid values >= 0); remapped to +big for min.
    for (int i = tid; i < IN_H * TX; i += NTHREADS) {
        int r = i >> 7;          // /128
        int c = i & (TX - 1);    // %128
        float mx = -1.0f, mn = 1e30f;
        #pragma unroll
        for (int k = 0; k < 9; ++k) {
            float v = sT[r][c + k];
            mx = fmaxf(mx, v);
            mn = fminf(mn, v < 0.0f ? 1e30f : v);
        }
        sHmax[r][c] = mx;
        sHmin[r][c] = mn;
    }
    __syncthreads();

    // ---- vertical pass + fused BCE + thread-local accumulate ----
    float acc = 0.0f;
    for (int i = tid; i < TY * TX; i += NTHREADS) {
        int r = i >> 7;
        int c = i & (TX - 1);
        float dil = -1.0f, ero = 1e30f;
        #pragma unroll
        for (int k = 0; k < 9; ++k) {
            dil = fmaxf(dil, sHmax[r + k][c]);
            ero = fminf(ero, sHmin[r + k][c]);
        }
        // center pixel always valid -> dil in {0,1}, ero in {0,1}
        float y = sT[r + HALO][c + HALO];
        float x = lg[(rowBase + r) * IMG_W + (colBase + c)];
        float w = 1.0f + 2.0f * (dil - ero);   // BOUNDARY_WEIGHT=3
        // stable BCE-with-logits: max(x,0) - x*y + log1p(exp(-|x|))
        float a  = fabsf(x);
        float t  = __builtin_exp2f(-a * 1.44269504088896340736f);
        float sp = __builtin_log2f(1.0f + t) * 0.69314718055994530942f;
        float pe = fmaxf(x, 0.0f) - x * y + sp;
        acc += w * pe;
    }

    // ---- block reduction: wave64 shuffle tree, then cross-wave via LDS ----
    #pragma unroll
    for (int off = 32; off > 0; off >>= 1)
        acc += __shfl_down(acc, off, 64);
    int lane = tid & 63, wv = tid >> 6;
    if (lane == 0) sRed[wv] = acc;
    __syncthreads();
    if (tid == 0) {
        float s = 0.0f;
        #pragma unroll
        for (int w2 = 0; w2 < NTHREADS / 64; ++w2) s += sRed[w2];
        // mean scale: 1/(16*1024*1024) = 2^-24 (exact)
        atomicAdd(out, s * (1.0f / 16777216.0f));
    }
}

extern "C" void kernel_launch(void* const* d_in, const int* in_sizes, int n_in,
                              void* d_out, int out_size, void* d_ws, size_t ws_size,
                              hipStream_t stream) {
    const float* logits  = (const float*)d_in[0];
    const float* targets = (const float*)d_in[1];
    float* out = (float*)d_out;

    // d_out is poisoned before timing and not re-poisoned between replays:
    // zero it every call (graph-capturable kernel, same stream).
    wbce_zero_kernel<<<dim3(1), dim3(1), 0, stream>>>(out);

    dim3 grid(IMG_W / TX, IMG_H / TY, BATCH);   // 8 x 64 x 16
    dim3 block(NTHREADS);
    wbce_kernel<<<grid, block, 0, stream>>>(logits, targets, out);
}

// Round 2
// 40.930 us; speedup vs baseline: 3.1946x; 3.1946x over previous
//
#include <hip/hip_runtime.h>

// Problem constants (match reference)
#define BATCH 16
#define IMG_H 1024
#define IMG_W 1024
#define WORDS 16            // 1024 cols / 64 bits
#define TY 32               // output rows per block
#define SROWS (TY + 8)      // staged rows incl. +-4 halo = 40
#define NT 1024             // threads per block (16 waves)
#define NWAVES (NT / 64)

typedef unsigned long long u64;

__global__ void wbce_zero_kernel(float* out) { out[0] = 0.0f; }

__global__ __launch_bounds__(NT, 2)
void wbce_kernel(const float* __restrict__ logits,
                 const float* __restrict__ targets,
                 float* __restrict__ out)
{
    // Bit-packed morphology: bit c of word w in a row = (target[row][w*64+c] > 0.5)
    __shared__ u64 sT [SROWS * WORDS];   // packed targets (halo rows included)
    __shared__ u64 sHD[SROWS * WORDS];   // horizontal 9-dilate (OR)
    __shared__ u64 sHE[SROWS * WORDS];   // horizontal 9-erode  (AND)
    __shared__ u64 sBnd[TY * WORDS];     // boundary bits = dil & ~ero
    __shared__ float sRed[NWAVES];

    const int tid  = threadIdx.x;
    const int lane = tid & 63;
    const int wv   = tid >> 6;
    const int rowBase = blockIdx.x * TY;
    const int b = blockIdx.y;

    const float* tgt = targets + (size_t)b * (IMG_H * IMG_W);
    const float* lg  = logits  + (size_t)b * (IMG_H * IMG_W);

    // ---- Phase A: pack targets into bitmasks via wave ballot ----
    // One wave packs 64 consecutive pixels per iteration (coalesced 256B load).
    for (int it = wv; it < SROWS * WORDS; it += NWAVES) {
        int sr = it >> 4;          // staged row (WORDS==16)
        int w  = it & 15;
        int gr = rowBase + sr - 4;
        float v = 0.0f;
        if (gr >= 0 && gr < IMG_H) v = tgt[gr * IMG_W + w * 64 + lane];
        u64 m = __ballot(v > 0.5f);
        if (lane == 0) sT[it] = m;
    }
    __syncthreads();

    // ---- Phase B: horizontal +-4 window OR/AND, one thread per word ----
    // OOB columns: dilate fill = 0 (neutral for max/-inf init),
    //              erode  fill = 1 (neutral for min/+inf init).
    for (int it = tid; it < SROWS * WORDS; it += NT) {
        int sr = it >> 4;
        int w  = it & 15;
        int gr = rowBase + sr - 4;
        u64 hd, he;
        if (gr < 0 || gr >= IMG_H) {
            hd = 0ULL;       // OOB row: ignored by vertical OR
            he = ~0ULL;      // OOB row: ignored by vertical AND
        } else {
            u64 C  = sT[it];
            u64 Pd = (w > 0)  ? sT[it - 1] : 0ULL;
            u64 Pe = (w > 0)  ? sT[it - 1] : ~0ULL;
            u64 Nd = (w < 15) ? sT[it + 1] : 0ULL;
            u64 Ne = (w < 15) ? sT[it + 1] : ~0ULL;
            u64 d = C, e = C;
            #pragma unroll
            for (int s = 1; s <= 4; ++s) {
                d |= (C >> s) | (Nd << (64 - s));
                d |= (C << s) | (Pd >> (64 - s));
                e &= (C >> s) | (Ne << (64 - s));
                e &= (C << s) | (Pe >> (64 - s));
            }
            hd = d; he = e;
        }
        sHD[it] = hd;
        sHE[it] = he;
    }
    __syncthreads();

    // ---- Phase B2: vertical 9-row OR/AND -> boundary bits ----
    for (int it = tid; it < TY * WORDS; it += NT) {
        int r = it >> 4;
        int w = it & 15;
        u64 d = 0ULL, e = ~0ULL;
        #pragma unroll
        for (int k = 0; k < 9; ++k) {
            d |= sHD[(r + k) * WORDS + w];
            e &= sHE[(r + k) * WORDS + w];
        }
        sBnd[it] = d & ~e;   // dil - ero in {0,1} since ero <= dil
    }
    __syncthreads();

    // ---- Phase C: fused BCE over logits, 4 px/thread/iter (float4) ----
    float acc = 0.0f;
    #pragma unroll
    for (int k = 0; k < (TY * IMG_W / 4) / NT; ++k) {
        int it  = tid + k * NT;
        int r   = it >> 8;          // 256 float4s per row
        int pos = it & 255;
        int w   = pos >> 4;         // word index: pos*4/64
        int sh  = (pos & 15) * 4;   // bit offset within word

        const float4 x4 = *(const float4*)(lg + (size_t)(rowBase + r) * IMG_W + pos * 4);
        unsigned int bb = (unsigned int)(sBnd[r * WORDS + w] >> sh);        // boundary bits
        unsigned int tb = (unsigned int)(sT[(r + 4) * WORDS + w] >> sh);    // target bits

        const float xs[4] = {x4.x, x4.y, x4.z, x4.w};
        #pragma unroll
        for (int j = 0; j < 4; ++j) {
            float x  = xs[j];
            float wg = 1.0f + 2.0f * (float)((bb >> j) & 1u);   // BOUNDARY_WEIGHT=3
            float y  = (float)((tb >> j) & 1u);
            // stable BCE-with-logits: max(x,0) - x*y + log1p(exp(-|x|))
            float a  = fabsf(x);
            float t  = __builtin_exp2f(a * -1.44269504088896340736f);
            float sp = __builtin_log2f(1.0f + t) * 0.69314718055994530942f;
            float pe = fmaxf(x, 0.0f) - x * y + sp;
            acc = fmaf(wg, pe, acc);
        }
    }

    // ---- block reduction: wave64 shuffle tree, cross-wave via LDS ----
    #pragma unroll
    for (int off = 32; off > 0; off >>= 1)
        acc += __shfl_down(acc, off, 64);
    if (lane == 0) sRed[wv] = acc;
    __syncthreads();
    if (tid == 0) {
        float s = 0.0f;
        #pragma unroll
        for (int i = 0; i < NWAVES; ++i) s += sRed[i];
        atomicAdd(out, s * (1.0f / 16777216.0f));   // mean: 1/2^24 exact
    }
}

extern "C" void kernel_launch(void* const* d_in, const int* in_sizes, int n_in,
                              void* d_out, int out_size, void* d_ws, size_t ws_size,
                              hipStream_t stream) {
    const float* logits  = (const float*)d_in[0];
    const float* targets = (const float*)d_in[1];
    float* out = (float*)d_out;

    // d_out is poisoned before timing and not re-poisoned between replays:
    // zero it every call (graph-capturable kernel, same stream).
    wbce_zero_kernel<<<dim3(1), dim3(1), 0, stream>>>(out);

    dim3 grid(IMG_H / TY, BATCH);   // 32 x 16 = 512 blocks, 16 waves each
    dim3 block(NT);
    wbce_kernel<<<grid, block, 0, stream>>>(logits, targets, out);
}